// Round 3
// baseline (349.262 us; speedup 1.0000x reference)
//
#include <hip/hip_runtime.h>
#include <hip/hip_bf16.h>

#define B_    16384
#define S_    37
#define F_    17
#define OWN_  9
#define NOUT_ 23
#define OBS_ROW 646   // 38*17

typedef __bf16 bf16x8 __attribute__((ext_vector_type(8)));
typedef __bf16 bf16x4 __attribute__((ext_vector_type(4)));
typedef float  f32x4  __attribute__((ext_vector_type(4)));

// swapped-operand MFMA: A = weight frag (W^T), B = activation frag (X^T)
// D[channel][row]: lane(q,l16) reg r -> channel = base + q*4 + r, row = l16
#define MFMA(a,b,c) __builtin_amdgcn_mfma_f32_16x16x32_bf16(a, b, c, 0, 0, 0)

// ---- fragment-linear weight layout in ws (bf16 elements) ----
// dst[(k>>3)*(Np*8) + n*8 + (k&7)] = W[k][n]  (zero-padded)
#define W1F_OFF   0        // Np=256, Kp=32   -> 8192
#define W2F_OFF   8192     // Np=256, Kp=256  -> 65536
#define W3F_OFF   73728    // Np=128, Kp=256  -> 32768
#define AW1F_OFF  106496   // Np=256, Kp=160  -> 40960
#define AW2F_OFF  147456   // Np=256, Kp=256  -> 65536
#define AW3F_OFF  212992   // Np=32,  Kp=256  -> 8192
#define VW1F_OFF  221184   // Np=256, Kp=160  -> 40960
#define VW2F_OFF  262144   // Np=256, Kp=256  -> 65536
#define VW3F_OFF  327680   // Np=16,  Kp=256  -> 4096
#define PREP_TOTAL8 41472  // total elements / 8

// Coalesced prep: thread t owns 8 consecutive layout elements (same (c,n),
// e=0..7). Reads src[(c*8+e)*Ns + n] are lane-coalesced over n (8 coalesced
// dword loads); write is one contiguous bf16x8 at dst + t_local*8.
__global__ void prep_kernel(const float* __restrict__ sW1, const float* __restrict__ sW2,
                            const float* __restrict__ sW3, const float* __restrict__ aW1,
                            const float* __restrict__ aW2, const float* __restrict__ aW3,
                            const float* __restrict__ vW1, const float* __restrict__ vW2,
                            const float* __restrict__ vW3, __bf16* __restrict__ ws)
{
    int j8 = blockIdx.x * 256 + threadIdx.x;
    const float* src; __bf16* dst; int Np, Ks, Ns;
    if (j8 < 1024)                { dst = ws + W1F_OFF;  src = sW1; Np = 256; Ks = 17;  Ns = 256; }
    else if ((j8 -= 1024) < 8192) { dst = ws + W2F_OFF;  src = sW2; Np = 256; Ks = 256; Ns = 256; }
    else if ((j8 -= 8192) < 4096) { dst = ws + W3F_OFF;  src = sW3; Np = 128; Ks = 256; Ns = 128; }
    else if ((j8 -= 4096) < 5120) { dst = ws + AW1F_OFF; src = aW1; Np = 256; Ks = 137; Ns = 256; }
    else if ((j8 -= 5120) < 8192) { dst = ws + AW2F_OFF; src = aW2; Np = 256; Ks = 256; Ns = 256; }
    else if ((j8 -= 8192) < 1024) { dst = ws + AW3F_OFF; src = aW3; Np = 32;  Ks = 256; Ns = 23;  }
    else if ((j8 -= 1024) < 5120) { dst = ws + VW1F_OFF; src = vW1; Np = 256; Ks = 137; Ns = 256; }
    else if ((j8 -= 5120) < 8192) { dst = ws + VW2F_OFF; src = vW2; Np = 256; Ks = 256; Ns = 256; }
    else { j8 -= 8192;              dst = ws + VW3F_OFF; src = vW3; Np = 16;  Ks = 256; Ns = 1;   }
    const int c = j8 / Np, n = j8 - c * Np;
    bf16x8 pk;
    #pragma unroll
    for (int e = 0; e < 8; ++e) {
        const int k = c * 8 + e;
        const float v = (k < Ks && n < Ns) ? src[k * Ns + n] : 0.f;
        pk[e] = (__bf16)v;
    }
    *(bf16x8*)(dst + (size_t)j8 * 8) = pk;
}

// 512 threads = 8 waves; block = 16 batch rows; M-tile = 128 rows (16 b x 8 s),
// 5 iters x 2 barriers. Seq-MLP weights in registers (136 VGPR). Staging of
// next s-group split T14-style: global loads at loop top (all 512 threads,
// 4-5 feats each), LDS writes after B1 (one barrier before consumption).
__global__ __launch_bounds__(512, 2) void fused_kernel(
    const float* __restrict__ obs,
    const float* __restrict__ sb1, const float* __restrict__ sb2, const float* __restrict__ sb3,
    const float* __restrict__ ab1, const float* __restrict__ ab2, const float* __restrict__ ab3,
    const float* __restrict__ vb1, const float* __restrict__ vb2, const float* __restrict__ vb3,
    const __bf16* __restrict__ ws, float* __restrict__ out)
{
    __shared__ __align__(16) char pool[148480];
    __bf16* act1 = (__bf16*)pool;                    // [32 kch][128 row][8] 64KB
    __bf16* act2 = (__bf16*)(pool + 65536);          // [32 kch][128 row][8] 64KB
    __bf16* xs0  = (__bf16*)(pool + 131072);         // [4 kch][128 row][8] 8KB
    __bf16* xs1  = (__bf16*)(pool + 139264);         // 8KB
    float*  sm0  = (float*)(pool + 147456);          // 128 f32
    float*  sm1  = (float*)(pool + 147968);          // 128 f32
    __bf16* catf = (__bf16*)(pool + 131072);         // [20 kch][16 row][8] (aliases xs0)
    float*  partial = (float*)pool;                  // [128 ch][16 b] f32 (aliases act1)

    const __bf16* W1f  = ws + W1F_OFF;
    const __bf16* W2f  = ws + W2F_OFF;
    const __bf16* W3f  = ws + W3F_OFF;
    const __bf16* AW1f = ws + AW1F_OFF;
    const __bf16* AW2f = ws + AW2F_OFF;
    const __bf16* AW3f = ws + AW3F_OFF;
    const __bf16* VW1f = ws + VW1F_OFF;
    const __bf16* VW2f = ws + VW2F_OFF;
    const __bf16* VW3f = ws + VW3F_OFF;

    const int tid  = threadIdx.x;
    const int wave = tid >> 6;
    const int lane = tid & 63;
    const int q    = lane >> 4;
    const int l16  = lane & 15;
    const int qh   = q >> 1;
    const int e4   = (q & 1) * 4;
    const int b0   = blockIdx.x * 16;
    const int nc   = wave & 3;   // L3 col-group
    const int mr   = wave >> 2;  // L3 row-group
    const f32x4 z4 = {0.f, 0.f, 0.f, 0.f};

    // staging role: 4 threads per row, 4-5 features each
    const int sr  = tid >> 2;          // row 0..127 = ssl*16 + sb
    const int sp  = tid & 3;           // feature part
    const int sb  = sr & 15;
    const int ssl = sr >> 4;
    const int nf  = (sp == 3) ? 5 : 4; // features sp*4 .. sp*4+nf-1
    const float* obs_row = obs + (size_t)(b0 + sb) * OBS_ROW;

    // ---- zero both xs buffers (pad chunks / padded rows stay zero) ----
    #pragma unroll
    for (int i = 0; i < 2; ++i)
        ((f32x4*)xs0)[tid + i * 512] = z4;   // 1024*16B = 16384B (xs0+xs1)

    // ---- load loop-invariant weights into registers ----
    bf16x8 w1f[2], w2f[8][2], w3f[2][8];
    f32x4 b1q[2], b2q[2], b3q[2];
    #pragma unroll
    for (int nt = 0; nt < 2; ++nt) {
        const int n = wave * 32 + nt * 16 + l16;
        w1f[nt] = *(const bf16x8*)(W1f + ((size_t)q * 256 + n) * 8);
        b1q[nt] = *(const f32x4*)(sb1 + wave * 32 + nt * 16 + q * 4);
        b2q[nt] = *(const f32x4*)(sb2 + wave * 32 + nt * 16 + q * 4);
        b3q[nt] = *(const f32x4*)(sb3 + nc * 32 + nt * 16 + q * 4);
        #pragma unroll
        for (int k = 0; k < 8; ++k) {
            w2f[k][nt] = *(const bf16x8*)(W2f + ((size_t)(k * 4 + q) * 256 + n) * 8);
            w3f[nt][k] = *(const bf16x8*)(W3f + ((size_t)(k * 4 + q) * 128 + nc * 32 + nt * 16 + l16) * 8);
        }
    }

    __syncthreads();  // zeros visible before prologue staging

    // ---- prologue: stage s-group 0 into xs0/sm0 (s = ssl, always < 37) ----
    {
        const float* p = obs_row + (ssl + 1) * F_ + sp * 4;
        float psum = 0.f;
        #pragma unroll
        for (int f = 0; f < 5; ++f) {
            if (f < nf) {
                const float v = p[f];
                psum += fabsf(v);
                const int c = sp * 4 + f;
                xs0[((c >> 3) * 128 + sr) * 8 + (c & 7)] = (__bf16)v;
            }
        }
        psum += __shfl_xor(psum, 1);
        psum += __shfl_xor(psum, 2);
        if (sp == 0) sm0[sr] = psum;
    }
    __syncthreads();  // xs0/sm0 ready

    f32x4 vsum[2] = {z4, z4};

    for (int it = 0; it < 5; ++it) {
        __bf16* xc  = (it & 1) ? xs1 : xs0;
        __bf16* xn  = (it & 1) ? xs0 : xs1;
        float*  smc = (it & 1) ? sm1 : sm0;
        float*  smn = (it & 1) ? sm0 : sm1;

        // ---- issue next-group global loads (consumed after B1) ----
        const int s_nx = (it + 1) * 8 + ssl;
        const bool st_valid = (it < 4) && (s_nx < S_);
        float stv[5];
        if (st_valid) {
            const float* p = obs_row + (s_nx + 1) * F_ + sp * 4;
            #pragma unroll
            for (int f = 0; f < 5; ++f)
                if (f < nf) stv[f] = p[f];
        }

        // ---- layer 1: X(128,32) x W1 -> act1, ch = wave*32+nt*16+q*4+r ----
        #pragma unroll
        for (int m = 0; m < 8; ++m) {
            const bf16x8 xm = *(const bf16x8*)(xc + (q * 128 + m * 16 + l16) * 8);
            #pragma unroll
            for (int nt = 0; nt < 2; ++nt) {
                const f32x4 h = MFMA(w1f[nt], xm, z4);
                float v0 = h[0] + b1q[nt][0]; v0 = v0 > 0.f ? v0 : 0.f;
                float v1 = h[1] + b1q[nt][1]; v1 = v1 > 0.f ? v1 : 0.f;
                float v2 = h[2] + b1q[nt][2]; v2 = v2 > 0.f ? v2 : 0.f;
                float v3 = h[3] + b1q[nt][3]; v3 = v3 > 0.f ? v3 : 0.f;
                const bf16x4 pk = {(__bf16)v0, (__bf16)v1, (__bf16)v2, (__bf16)v3};
                *(bf16x4*)(act1 + ((wave * 4 + nt * 2 + qh) * 128 + m * 16 + l16) * 8 + e4) = pk;
            }
        }
        __syncthreads();  // B1: act1 ready; prev-iter act2 readers (L3) done

        // ---- staging writes into xn/smn (consumers after B2) ----
        if (it < 4) {
            float psum = 0.f;
            if (st_valid) {
                #pragma unroll
                for (int f = 0; f < 5; ++f) {
                    if (f < nf) {
                        const float v = stv[f];
                        psum += fabsf(v);
                        const int c = sp * 4 + f;
                        xn[((c >> 3) * 128 + sr) * 8 + (c & 7)] = (__bf16)v;
                    }
                }
            }
            psum += __shfl_xor(psum, 1);
            psum += __shfl_xor(psum, 2);
            if (sp == 0) smn[sr] = st_valid ? psum : 0.f;
        }

        // ---- layer 2: (128,256) x (256,256) -> act2, two 64-row halves ----
        #pragma unroll
        for (int mh = 0; mh < 2; ++mh) {
            f32x4 h2[2][4];
            #pragma unroll
            for (int nt = 0; nt < 2; ++nt)
                #pragma unroll
                for (int m = 0; m < 4; ++m) h2[nt][m] = z4;
            #pragma unroll
            for (int k = 0; k < 8; ++k) {
                const int k8 = k * 4 + q;
                #pragma unroll
                for (int m = 0; m < 4; ++m) {
                    const bf16x8 a = *(const bf16x8*)(act1 + (k8 * 128 + mh * 64 + m * 16 + l16) * 8);
                    h2[0][m] = MFMA(w2f[k][0], a, h2[0][m]);
                    h2[1][m] = MFMA(w2f[k][1], a, h2[1][m]);
                }
            }
            #pragma unroll
            for (int nt = 0; nt < 2; ++nt)
                #pragma unroll
                for (int m = 0; m < 4; ++m) {
                    float v0 = h2[nt][m][0] + b2q[nt][0]; v0 = v0 > 0.f ? v0 : 0.f;
                    float v1 = h2[nt][m][1] + b2q[nt][1]; v1 = v1 > 0.f ? v1 : 0.f;
                    float v2 = h2[nt][m][2] + b2q[nt][2]; v2 = v2 > 0.f ? v2 : 0.f;
                    float v3 = h2[nt][m][3] + b2q[nt][3]; v3 = v3 > 0.f ? v3 : 0.f;
                    const bf16x4 pk = {(__bf16)v0, (__bf16)v1, (__bf16)v2, (__bf16)v3};
                    *(bf16x4*)(act2 + ((wave * 4 + nt * 2 + qh) * 128 + mh * 64 + m * 16 + l16) * 8 + e4) = pk;
                }
        }
        __syncthreads();  // B2: act2 ready; xn writes done

        // ---- layer 3 (2D split): cols nc*32.., rows mr*64 + mi*16 ; pool ----
        #pragma unroll
        for (int mi = 0; mi < 4; ++mi) {
            f32x4 h3[2] = {z4, z4};
            #pragma unroll
            for (int k = 0; k < 8; ++k) {
                const int k8 = k * 4 + q;
                const bf16x8 a = *(const bf16x8*)(act2 + (k8 * 128 + mr * 64 + mi * 16 + l16) * 8);
                h3[0] = MFMA(w3f[0][k], a, h3[0]);
                h3[1] = MFMA(w3f[1][k], a, h3[1]);
            }
            const float mv = smc[mr * 64 + mi * 16 + l16];
            #pragma unroll
            for (int nt = 0; nt < 2; ++nt)
                #pragma unroll
                for (int r = 0; r < 4; ++r) {
                    float v = h3[nt][r] + b3q[nt][r];
                    v = v > 0.f ? v : 0.f;
                    vsum[nt][r] += (mv != 0.f) ? v : 0.f;
                }
        }
        // no barrier: next L1 writes act1 (act1 readers finished before B2)
    }

    // ---- combine L3 partials across mr; stage cat ----
    if (mr == 0) {
        #pragma unroll
        for (int nt = 0; nt < 2; ++nt)
            #pragma unroll
            for (int r = 0; r < 4; ++r)
                partial[(nc * 32 + nt * 16 + q * 4 + r) * 16 + l16] = vsum[nt][r];
    }
    // s_own + zero-pad chunks of catf (xs0 dead: last read was L1(it=4) pre-B1)
    if (tid < 16) {
        const float* p = obs + (size_t)(b0 + tid) * OBS_ROW;  // s_own
        #pragma unroll
        for (int c = 0; c < 8; ++c) catf[(16 * 16 + tid) * 8 + c] = (__bf16)p[c];
        catf[(17 * 16 + tid) * 8 + 0] = (__bf16)p[8];
        #pragma unroll
        for (int c = 1; c < 8; ++c) catf[(17 * 16 + tid) * 8 + c] = (__bf16)0.f;
    } else if (tid < 32) {
        const int rr = tid - 16;
        #pragma unroll
        for (int c = 0; c < 8; ++c) {
            catf[(18 * 16 + rr) * 8 + c] = (__bf16)0.f;
            catf[(19 * 16 + rr) * 8 + c] = (__bf16)0.f;
        }
    }
    __syncthreads();  // partials + s_own visible

    if (mr == 1) {
        #pragma unroll
        for (int nt = 0; nt < 2; ++nt) {
            f32x4 t = vsum[nt];
            #pragma unroll
            for (int r = 0; r < 4; ++r)
                t[r] += partial[(nc * 32 + nt * 16 + q * 4 + r) * 16 + l16];
            const bf16x4 pk = {(__bf16)t[0], (__bf16)t[1], (__bf16)t[2], (__bf16)t[3]};
            *(bf16x4*)(catf + ((nc * 4 + nt * 2 + qh) * 16 + l16) * 8 + e4) = pk;
        }
    }
    __syncthreads();  // catf ready (partial dead, act1 writable)

    // ---- head layer 1: (16,160) x (160,256), both heads -> act1 ----
    {
        f32x4 ha[2] = {z4, z4}, hv[2] = {z4, z4};
        #pragma unroll
        for (int k = 0; k < 5; ++k) {
            const int k8 = k * 4 + q;
            const bf16x8 ca = *(const bf16x8*)(catf + (k8 * 16 + l16) * 8);
            #pragma unroll
            for (int nt = 0; nt < 2; ++nt) {
                const int n = wave * 32 + nt * 16 + l16;
                const bf16x8 ba = *(const bf16x8*)(AW1f + ((size_t)k8 * 256 + n) * 8);
                const bf16x8 bv = *(const bf16x8*)(VW1f + ((size_t)k8 * 256 + n) * 8);
                ha[nt] = MFMA(ba, ca, ha[nt]);
                hv[nt] = MFMA(bv, ca, hv[nt]);
            }
        }
        #pragma unroll
        for (int nt = 0; nt < 2; ++nt) {
            const f32x4 ab_ = *(const f32x4*)(ab1 + wave * 32 + nt * 16 + q * 4);
            const f32x4 vb_ = *(const f32x4*)(vb1 + wave * 32 + nt * 16 + q * 4);
            float a0 = ha[nt][0] + ab_[0]; a0 = a0 > 0.f ? a0 : 0.f;
            float a1 = ha[nt][1] + ab_[1]; a1 = a1 > 0.f ? a1 : 0.f;
            float a2 = ha[nt][2] + ab_[2]; a2 = a2 > 0.f ? a2 : 0.f;
            float a3 = ha[nt][3] + ab_[3]; a3 = a3 > 0.f ? a3 : 0.f;
            float u0 = hv[nt][0] + vb_[0]; u0 = u0 > 0.f ? u0 : 0.f;
            float u1 = hv[nt][1] + vb_[1]; u1 = u1 > 0.f ? u1 : 0.f;
            float u2 = hv[nt][2] + vb_[2]; u2 = u2 > 0.f ? u2 : 0.f;
            float u3 = hv[nt][3] + vb_[3]; u3 = u3 > 0.f ? u3 : 0.f;
            const bf16x4 pa = {(__bf16)a0, (__bf16)a1, (__bf16)a2, (__bf16)a3};
            const bf16x4 pv = {(__bf16)u0, (__bf16)u1, (__bf16)u2, (__bf16)u3};
            const int c = wave * 4 + nt * 2 + qh;
            *(bf16x4*)(act1 + (c * 128 + l16) * 8 + e4)      = pa;  // actor rows 0..15
            *(bf16x4*)(act1 + (c * 128 + 16 + l16) * 8 + e4) = pv;  // value rows 16..31
        }
    }
    __syncthreads();

    // ---- head layer 2: (16,256) x (256,256), both heads -> act2 ----
    {
        f32x4 ha[2] = {z4, z4}, hv[2] = {z4, z4};
        #pragma unroll
        for (int k = 0; k < 8; ++k) {
            const int k8 = k * 4 + q;
            const bf16x8 a0 = *(const bf16x8*)(act1 + (k8 * 128 + l16) * 8);
            const bf16x8 a1 = *(const bf16x8*)(act1 + (k8 * 128 + 16 + l16) * 8);
            #pragma unroll
            for (int nt = 0; nt < 2; ++nt) {
                const int n = wave * 32 + nt * 16 + l16;
                const bf16x8 ba = *(const bf16x8*)(AW2f + ((size_t)k8 * 256 + n) * 8);
                const bf16x8 bv = *(const bf16x8*)(VW2f + ((size_t)k8 * 256 + n) * 8);
                ha[nt] = MFMA(ba, a0, ha[nt]);
                hv[nt] = MFMA(bv, a1, hv[nt]);
            }
        }
        #pragma unroll
        for (int nt = 0; nt < 2; ++nt) {
            const f32x4 ab_ = *(const f32x4*)(ab2 + wave * 32 + nt * 16 + q * 4);
            const f32x4 vb_ = *(const f32x4*)(vb2 + wave * 32 + nt * 16 + q * 4);
            float a0 = ha[nt][0] + ab_[0]; a0 = a0 > 0.f ? a0 : 0.f;
            float a1 = ha[nt][1] + ab_[1]; a1 = a1 > 0.f ? a1 : 0.f;
            float a2 = ha[nt][2] + ab_[2]; a2 = a2 > 0.f ? a2 : 0.f;
            float a3 = ha[nt][3] + ab_[3]; a3 = a3 > 0.f ? a3 : 0.f;
            float u0 = hv[nt][0] + vb_[0]; u0 = u0 > 0.f ? u0 : 0.f;
            float u1 = hv[nt][1] + vb_[1]; u1 = u1 > 0.f ? u1 : 0.f;
            float u2 = hv[nt][2] + vb_[2]; u2 = u2 > 0.f ? u2 : 0.f;
            float u3 = hv[nt][3] + vb_[3]; u3 = u3 > 0.f ? u3 : 0.f;
            const bf16x4 pa = {(__bf16)a0, (__bf16)a1, (__bf16)a2, (__bf16)a3};
            const bf16x4 pv = {(__bf16)u0, (__bf16)u1, (__bf16)u2, (__bf16)u3};
            const int c = wave * 4 + nt * 2 + qh;
            *(bf16x4*)(act2 + (c * 128 + l16) * 8 + e4)      = pa;
            *(bf16x4*)(act2 + (c * 128 + 16 + l16) * 8 + e4) = pv;
        }
    }
    __syncthreads();

    // ---- head layer 3 ----
    if (wave < 2) {       // actor logits: channel n = wave*16 + q*4 + r, batch = l16
        f32x4 acc = z4;
        #pragma unroll
        for (int k = 0; k < 8; ++k) {
            const int k8 = k * 4 + q;
            const bf16x8 a0 = *(const bf16x8*)(act2 + (k8 * 128 + l16) * 8);
            const bf16x8 bf = *(const bf16x8*)(AW3f + ((size_t)k8 * 32 + wave * 16 + l16) * 8);
            acc = MFMA(bf, a0, acc);
        }
        const int nb = wave * 16 + q * 4;
        #pragma unroll
        for (int r = 0; r < 4; ++r) {
            const int n = nb + r;
            if (n < NOUT_)
                out[(size_t)(b0 + l16) * NOUT_ + n] = acc[r] + ab3[n];
        }
    } else if (wave == 2) {  // value: channel 0 lives in q==0, reg 0
        f32x4 acc = z4;
        #pragma unroll
        for (int k = 0; k < 8; ++k) {
            const int k8 = k * 4 + q;
            const bf16x8 a1 = *(const bf16x8*)(act2 + (k8 * 128 + 16 + l16) * 8);
            const bf16x8 bf = *(const bf16x8*)(VW3f + ((size_t)k8 * 16 + l16) * 8);
            acc = MFMA(bf, a1, acc);
        }
        if (q == 0)
            out[(size_t)B_ * NOUT_ + b0 + l16] = acc[0] + vb3[0];
    }
}

extern "C" void kernel_launch(void* const* d_in, const int* in_sizes, int n_in,
                              void* d_out, int out_size, void* d_ws, size_t ws_size,
                              hipStream_t stream)
{
    const float* obs = (const float*)d_in[0];
    const float* sW1 = (const float*)d_in[1];
    const float* sb1 = (const float*)d_in[2];
    const float* sW2 = (const float*)d_in[3];
    const float* sb2 = (const float*)d_in[4];
    const float* sW3 = (const float*)d_in[5];
    const float* sb3 = (const float*)d_in[6];
    const float* aW1 = (const float*)d_in[7];
    const float* ab1 = (const float*)d_in[8];
    const float* aW2 = (const float*)d_in[9];
    const float* ab2 = (const float*)d_in[10];
    const float* aW3 = (const float*)d_in[11];
    const float* ab3 = (const float*)d_in[12];
    const float* vW1 = (const float*)d_in[13];
    const float* vb1 = (const float*)d_in[14];
    const float* vW2 = (const float*)d_in[15];
    const float* vb2 = (const float*)d_in[16];
    const float* vW3 = (const float*)d_in[17];
    const float* vb3 = (const float*)d_in[18];

    __bf16* ws = (__bf16*)d_ws;
    float* out = (float*)d_out;

    hipLaunchKernelGGL(prep_kernel, dim3(PREP_TOTAL8 / 256), dim3(256), 0, stream,
                       sW1, sW2, sW3, aW1, aW2, aW3, vW1, vW2, vW3, ws);
    hipLaunchKernelGGL(fused_kernel, dim3(B_ / 16), dim3(512), 0, stream,
                       obs, sb1, sb2, sb3, ab1, ab2, ab3, vb1, vb2, vb3,
                       (const __bf16*)ws, out);
}

// Round 4
// 260.218 us; speedup vs baseline: 1.3422x; 1.3422x over previous
//
#include <hip/hip_runtime.h>
#include <hip/hip_bf16.h>

#define B_    16384
#define S_    37
#define F_    17
#define OWN_  9
#define NOUT_ 23
#define OBS_ROW 646   // 38*17

typedef __bf16 bf16x8 __attribute__((ext_vector_type(8)));
typedef __bf16 bf16x4 __attribute__((ext_vector_type(4)));
typedef float  f32x4  __attribute__((ext_vector_type(4)));

// swapped-operand MFMA: A = weight frag (W^T), B = activation frag (X^T)
// D[channel][row]: lane(q,l16) reg r -> channel = base + q*4 + r, row = l16
#define MFMA(a,b,c) __builtin_amdgcn_mfma_f32_16x16x32_bf16(a, b, c, 0, 0, 0)

// ---- fragment-linear weight layout in ws (bf16 elements) ----
// dst[(k>>3)*(Np*8) + n*8 + (k&7)] = W[k][n]  (zero-padded)
#define W1F_OFF   0        // Np=256, Kp=32   -> 8192
#define W2F_OFF   8192     // Np=256, Kp=256  -> 65536
#define W3F_OFF   73728    // Np=128, Kp=256  -> 32768
#define AW1F_OFF  106496   // Np=256, Kp=160  -> 40960
#define AW2F_OFF  147456   // Np=256, Kp=256  -> 65536
#define AW3F_OFF  212992   // Np=32,  Kp=256  -> 8192
#define VW1F_OFF  221184   // Np=256, Kp=160  -> 40960
#define VW2F_OFF  262144   // Np=256, Kp=256  -> 65536
#define VW3F_OFF  327680   // Np=16,  Kp=256  -> 4096
#define PREP_TOTAL8 41472  // total elements / 8

// Coalesced prep: thread t owns 8 consecutive layout elements (same (c,n),
// e=0..7). Reads src[(c*8+e)*Ns + n] are lane-coalesced over n; write is one
// contiguous bf16x8 at dst + j8*8.
__global__ void prep_kernel(const float* __restrict__ sW1, const float* __restrict__ sW2,
                            const float* __restrict__ sW3, const float* __restrict__ aW1,
                            const float* __restrict__ aW2, const float* __restrict__ aW3,
                            const float* __restrict__ vW1, const float* __restrict__ vW2,
                            const float* __restrict__ vW3, __bf16* __restrict__ ws)
{
    int j8 = blockIdx.x * 256 + threadIdx.x;
    const float* src; __bf16* dst; int Np, Ks, Ns;
    if (j8 < 1024)                { dst = ws + W1F_OFF;  src = sW1; Np = 256; Ks = 17;  Ns = 256; }
    else if ((j8 -= 1024) < 8192) { dst = ws + W2F_OFF;  src = sW2; Np = 256; Ks = 256; Ns = 256; }
    else if ((j8 -= 8192) < 4096) { dst = ws + W3F_OFF;  src = sW3; Np = 128; Ks = 256; Ns = 128; }
    else if ((j8 -= 4096) < 5120) { dst = ws + AW1F_OFF; src = aW1; Np = 256; Ks = 137; Ns = 256; }
    else if ((j8 -= 5120) < 8192) { dst = ws + AW2F_OFF; src = aW2; Np = 256; Ks = 256; Ns = 256; }
    else if ((j8 -= 8192) < 1024) { dst = ws + AW3F_OFF; src = aW3; Np = 32;  Ks = 256; Ns = 23;  }
    else if ((j8 -= 1024) < 5120) { dst = ws + VW1F_OFF; src = vW1; Np = 256; Ks = 137; Ns = 256; }
    else if ((j8 -= 5120) < 8192) { dst = ws + VW2F_OFF; src = vW2; Np = 256; Ks = 256; Ns = 256; }
    else { j8 -= 8192;              dst = ws + VW3F_OFF; src = vW3; Np = 16;  Ks = 256; Ns = 1;   }
    const int c = j8 / Np, n = j8 - c * Np;
    bf16x8 pk;
    #pragma unroll
    for (int e = 0; e < 8; ++e) {
        const int k = c * 8 + e;
        const float v = (k < Ks && n < Ns) ? src[k * Ns + n] : 0.f;
        pk[e] = (__bf16)v;
    }
    *(bf16x8*)(dst + (size_t)j8 * 8) = pk;
}

// 512 threads = 8 waves; block = 16 batch rows; M-tile = 128 rows (16 b x 8 s),
// 5 iters x 2 barriers. Seq-MLP weights in registers (136 VGPR).
// R4 spill fix: waves_per_eu(2,2) pins allocator at the real occupancy
// (LDS=145KB forces 1 block/CU = 2 waves/EU -> 256-reg budget); L2 done in
// 4 quarter-passes (h2 peak 16 f32) with unroll-1 fences; L1 unroll 2.
__global__ __launch_bounds__(512) __attribute__((amdgpu_waves_per_eu(2, 2)))
void fused_kernel(
    const float* __restrict__ obs,
    const float* __restrict__ sb1, const float* __restrict__ sb2, const float* __restrict__ sb3,
    const float* __restrict__ ab1, const float* __restrict__ ab2, const float* __restrict__ ab3,
    const float* __restrict__ vb1, const float* __restrict__ vb2, const float* __restrict__ vb3,
    const __bf16* __restrict__ ws, float* __restrict__ out)
{
    __shared__ __align__(16) char pool[148480];
    __bf16* act1 = (__bf16*)pool;                    // [32 kch][128 row][8] 64KB
    __bf16* act2 = (__bf16*)(pool + 65536);          // [32 kch][128 row][8] 64KB
    __bf16* xs0  = (__bf16*)(pool + 131072);         // [4 kch][128 row][8] 8KB
    __bf16* xs1  = (__bf16*)(pool + 139264);         // 8KB
    float*  sm0  = (float*)(pool + 147456);          // 128 f32
    float*  sm1  = (float*)(pool + 147968);          // 128 f32
    __bf16* catf = (__bf16*)(pool + 131072);         // [20 kch][16 row][8] (aliases xs0)
    float*  partial = (float*)pool;                  // [128 ch][16 b] f32 (aliases act1)

    const __bf16* W1f  = ws + W1F_OFF;
    const __bf16* W2f  = ws + W2F_OFF;
    const __bf16* W3f  = ws + W3F_OFF;
    const __bf16* AW1f = ws + AW1F_OFF;
    const __bf16* AW2f = ws + AW2F_OFF;
    const __bf16* AW3f = ws + AW3F_OFF;
    const __bf16* VW1f = ws + VW1F_OFF;
    const __bf16* VW2f = ws + VW2F_OFF;
    const __bf16* VW3f = ws + VW3F_OFF;

    const int tid  = threadIdx.x;
    const int wave = tid >> 6;
    const int lane = tid & 63;
    const int q    = lane >> 4;
    const int l16  = lane & 15;
    const int qh   = q >> 1;
    const int e4   = (q & 1) * 4;
    const int b0   = blockIdx.x * 16;
    const int nc   = wave & 3;   // L3 col-group
    const int mr   = wave >> 2;  // L3 row-group
    const f32x4 z4 = {0.f, 0.f, 0.f, 0.f};

    // staging role: 4 threads per row, 4-5 features each
    const int sr  = tid >> 2;          // row 0..127 = ssl*16 + sb
    const int sp  = tid & 3;           // feature part
    const int sb  = sr & 15;
    const int ssl = sr >> 4;
    const int nf  = (sp == 3) ? 5 : 4; // features sp*4 .. sp*4+nf-1
    const float* obs_row = obs + (size_t)(b0 + sb) * OBS_ROW;

    // ---- zero both xs buffers (pad chunks / padded rows stay zero) ----
    #pragma unroll
    for (int i = 0; i < 2; ++i)
        ((f32x4*)xs0)[tid + i * 512] = z4;   // 1024*16B = 16384B (xs0+xs1)

    // ---- load loop-invariant weights into registers ----
    bf16x8 w1f[2], w2f[8][2], w3f[2][8];
    f32x4 b1q[2], b2q[2], b3q[2];
    #pragma unroll
    for (int nt = 0; nt < 2; ++nt) {
        const int n = wave * 32 + nt * 16 + l16;
        w1f[nt] = *(const bf16x8*)(W1f + ((size_t)q * 256 + n) * 8);
        b1q[nt] = *(const f32x4*)(sb1 + wave * 32 + nt * 16 + q * 4);
        b2q[nt] = *(const f32x4*)(sb2 + wave * 32 + nt * 16 + q * 4);
        b3q[nt] = *(const f32x4*)(sb3 + nc * 32 + nt * 16 + q * 4);
        #pragma unroll
        for (int k = 0; k < 8; ++k) {
            w2f[k][nt] = *(const bf16x8*)(W2f + ((size_t)(k * 4 + q) * 256 + n) * 8);
            w3f[nt][k] = *(const bf16x8*)(W3f + ((size_t)(k * 4 + q) * 128 + nc * 32 + nt * 16 + l16) * 8);
        }
    }

    __syncthreads();  // zeros visible before prologue staging

    // ---- prologue: stage s-group 0 into xs0/sm0 (s = ssl, always < 37) ----
    {
        const float* p = obs_row + (ssl + 1) * F_ + sp * 4;
        float psum = 0.f;
        #pragma unroll
        for (int f = 0; f < 5; ++f) {
            if (f < nf) {
                const float v = p[f];
                psum += fabsf(v);
                const int c = sp * 4 + f;
                xs0[((c >> 3) * 128 + sr) * 8 + (c & 7)] = (__bf16)v;
            }
        }
        psum += __shfl_xor(psum, 1);
        psum += __shfl_xor(psum, 2);
        if (sp == 0) sm0[sr] = psum;
    }
    __syncthreads();  // xs0/sm0 ready

    f32x4 vsum[2] = {z4, z4};

    for (int it = 0; it < 5; ++it) {
        __bf16* xc  = (it & 1) ? xs1 : xs0;
        __bf16* xn  = (it & 1) ? xs0 : xs1;
        float*  smc = (it & 1) ? sm1 : sm0;
        float*  smn = (it & 1) ? sm0 : sm1;

        // ---- issue next-group global loads (consumed after B1) ----
        const int s_nx = (it + 1) * 8 + ssl;
        const bool st_valid = (it < 4) && (s_nx < S_);
        float stv[5];
        if (st_valid) {
            const float* p = obs_row + (s_nx + 1) * F_ + sp * 4;
            #pragma unroll
            for (int f = 0; f < 5; ++f)
                if (f < nf) stv[f] = p[f];
        }

        // ---- layer 1: X(128,32) x W1 -> act1, ch = wave*32+nt*16+q*4+r ----
        #pragma unroll 2
        for (int m = 0; m < 8; ++m) {
            const bf16x8 xm = *(const bf16x8*)(xc + (q * 128 + m * 16 + l16) * 8);
            #pragma unroll
            for (int nt = 0; nt < 2; ++nt) {
                const f32x4 h = MFMA(w1f[nt], xm, z4);
                float v0 = h[0] + b1q[nt][0]; v0 = v0 > 0.f ? v0 : 0.f;
                float v1 = h[1] + b1q[nt][1]; v1 = v1 > 0.f ? v1 : 0.f;
                float v2 = h[2] + b1q[nt][2]; v2 = v2 > 0.f ? v2 : 0.f;
                float v3 = h[3] + b1q[nt][3]; v3 = v3 > 0.f ? v3 : 0.f;
                const bf16x4 pk = {(__bf16)v0, (__bf16)v1, (__bf16)v2, (__bf16)v3};
                *(bf16x4*)(act1 + ((wave * 4 + nt * 2 + qh) * 128 + m * 16 + l16) * 8 + e4) = pk;
            }
        }
        __syncthreads();  // B1: act1 ready; prev-iter act2 readers (L3) done

        // ---- staging writes into xn/smn (consumers after B2) ----
        if (it < 4) {
            float psum = 0.f;
            if (st_valid) {
                #pragma unroll
                for (int f = 0; f < 5; ++f) {
                    if (f < nf) {
                        const float v = stv[f];
                        psum += fabsf(v);
                        const int c = sp * 4 + f;
                        xn[((c >> 3) * 128 + sr) * 8 + (c & 7)] = (__bf16)v;
                    }
                }
            }
            psum += __shfl_xor(psum, 1);
            psum += __shfl_xor(psum, 2);
            if (sp == 0) smn[sr] = st_valid ? psum : 0.f;
        }

        // ---- layer 2: (128,256) x (256,256) -> act2, four 32-row quarters ----
        #pragma unroll 1
        for (int mq = 0; mq < 4; ++mq) {
            f32x4 h2[2][2];
            #pragma unroll
            for (int nt = 0; nt < 2; ++nt)
                #pragma unroll
                for (int m = 0; m < 2; ++m) h2[nt][m] = z4;
            #pragma unroll
            for (int k = 0; k < 8; ++k) {
                const int k8 = k * 4 + q;
                #pragma unroll
                for (int m = 0; m < 2; ++m) {
                    const bf16x8 a = *(const bf16x8*)(act1 + (k8 * 128 + mq * 32 + m * 16 + l16) * 8);
                    h2[0][m] = MFMA(w2f[k][0], a, h2[0][m]);
                    h2[1][m] = MFMA(w2f[k][1], a, h2[1][m]);
                }
            }
            #pragma unroll
            for (int nt = 0; nt < 2; ++nt)
                #pragma unroll
                for (int m = 0; m < 2; ++m) {
                    float v0 = h2[nt][m][0] + b2q[nt][0]; v0 = v0 > 0.f ? v0 : 0.f;
                    float v1 = h2[nt][m][1] + b2q[nt][1]; v1 = v1 > 0.f ? v1 : 0.f;
                    float v2 = h2[nt][m][2] + b2q[nt][2]; v2 = v2 > 0.f ? v2 : 0.f;
                    float v3 = h2[nt][m][3] + b2q[nt][3]; v3 = v3 > 0.f ? v3 : 0.f;
                    const bf16x4 pk = {(__bf16)v0, (__bf16)v1, (__bf16)v2, (__bf16)v3};
                    *(bf16x4*)(act2 + ((wave * 4 + nt * 2 + qh) * 128 + mq * 32 + m * 16 + l16) * 8 + e4) = pk;
                }
        }
        __syncthreads();  // B2: act2 ready; xn writes done

        // ---- layer 3 (2D split): cols nc*32.., rows mr*64 + mi*16 ; pool ----
        #pragma unroll 1
        for (int mi = 0; mi < 4; ++mi) {
            f32x4 h3[2] = {z4, z4};
            #pragma unroll
            for (int k = 0; k < 8; ++k) {
                const int k8 = k * 4 + q;
                const bf16x8 a = *(const bf16x8*)(act2 + (k8 * 128 + mr * 64 + mi * 16 + l16) * 8);
                h3[0] = MFMA(w3f[0][k], a, h3[0]);
                h3[1] = MFMA(w3f[1][k], a, h3[1]);
            }
            const float mv = smc[mr * 64 + mi * 16 + l16];
            #pragma unroll
            for (int nt = 0; nt < 2; ++nt)
                #pragma unroll
                for (int r = 0; r < 4; ++r) {
                    float v = h3[nt][r] + b3q[nt][r];
                    v = v > 0.f ? v : 0.f;
                    vsum[nt][r] += (mv != 0.f) ? v : 0.f;
                }
        }
        // no barrier: next L1 writes act1 (act1 readers finished before B2)
    }

    // ---- combine L3 partials across mr; stage cat ----
    if (mr == 0) {
        #pragma unroll
        for (int nt = 0; nt < 2; ++nt)
            #pragma unroll
            for (int r = 0; r < 4; ++r)
                partial[(nc * 32 + nt * 16 + q * 4 + r) * 16 + l16] = vsum[nt][r];
    }
    // s_own + zero-pad chunks of catf (xs0 dead: last read was L1(it=4) pre-B1)
    if (tid < 16) {
        const float* p = obs + (size_t)(b0 + tid) * OBS_ROW;  // s_own
        #pragma unroll
        for (int c = 0; c < 8; ++c) catf[(16 * 16 + tid) * 8 + c] = (__bf16)p[c];
        catf[(17 * 16 + tid) * 8 + 0] = (__bf16)p[8];
        #pragma unroll
        for (int c = 1; c < 8; ++c) catf[(17 * 16 + tid) * 8 + c] = (__bf16)0.f;
    } else if (tid < 32) {
        const int rr = tid - 16;
        #pragma unroll
        for (int c = 0; c < 8; ++c) {
            catf[(18 * 16 + rr) * 8 + c] = (__bf16)0.f;
            catf[(19 * 16 + rr) * 8 + c] = (__bf16)0.f;
        }
    }
    __syncthreads();  // partials + s_own visible

    if (mr == 1) {
        #pragma unroll
        for (int nt = 0; nt < 2; ++nt) {
            f32x4 t = vsum[nt];
            #pragma unroll
            for (int r = 0; r < 4; ++r)
                t[r] += partial[(nc * 32 + nt * 16 + q * 4 + r) * 16 + l16];
            const bf16x4 pk = {(__bf16)t[0], (__bf16)t[1], (__bf16)t[2], (__bf16)t[3]};
            *(bf16x4*)(catf + ((nc * 4 + nt * 2 + qh) * 16 + l16) * 8 + e4) = pk;
        }
    }
    __syncthreads();  // catf ready (partial dead, act1 writable)

    // ---- head layer 1: (16,160) x (160,256), both heads -> act1 ----
    {
        f32x4 ha[2] = {z4, z4}, hv[2] = {z4, z4};
        #pragma unroll
        for (int k = 0; k < 5; ++k) {
            const int k8 = k * 4 + q;
            const bf16x8 ca = *(const bf16x8*)(catf + (k8 * 16 + l16) * 8);
            #pragma unroll
            for (int nt = 0; nt < 2; ++nt) {
                const int n = wave * 32 + nt * 16 + l16;
                const bf16x8 ba = *(const bf16x8*)(AW1f + ((size_t)k8 * 256 + n) * 8);
                const bf16x8 bv = *(const bf16x8*)(VW1f + ((size_t)k8 * 256 + n) * 8);
                ha[nt] = MFMA(ba, ca, ha[nt]);
                hv[nt] = MFMA(bv, ca, hv[nt]);
            }
        }
        #pragma unroll
        for (int nt = 0; nt < 2; ++nt) {
            const f32x4 ab_ = *(const f32x4*)(ab1 + wave * 32 + nt * 16 + q * 4);
            const f32x4 vb_ = *(const f32x4*)(vb1 + wave * 32 + nt * 16 + q * 4);
            float a0 = ha[nt][0] + ab_[0]; a0 = a0 > 0.f ? a0 : 0.f;
            float a1 = ha[nt][1] + ab_[1]; a1 = a1 > 0.f ? a1 : 0.f;
            float a2 = ha[nt][2] + ab_[2]; a2 = a2 > 0.f ? a2 : 0.f;
            float a3 = ha[nt][3] + ab_[3]; a3 = a3 > 0.f ? a3 : 0.f;
            float u0 = hv[nt][0] + vb_[0]; u0 = u0 > 0.f ? u0 : 0.f;
            float u1 = hv[nt][1] + vb_[1]; u1 = u1 > 0.f ? u1 : 0.f;
            float u2 = hv[nt][2] + vb_[2]; u2 = u2 > 0.f ? u2 : 0.f;
            float u3 = hv[nt][3] + vb_[3]; u3 = u3 > 0.f ? u3 : 0.f;
            const bf16x4 pa = {(__bf16)a0, (__bf16)a1, (__bf16)a2, (__bf16)a3};
            const bf16x4 pv = {(__bf16)u0, (__bf16)u1, (__bf16)u2, (__bf16)u3};
            const int c = wave * 4 + nt * 2 + qh;
            *(bf16x4*)(act1 + (c * 128 + l16) * 8 + e4)      = pa;  // actor rows 0..15
            *(bf16x4*)(act1 + (c * 128 + 16 + l16) * 8 + e4) = pv;  // value rows 16..31
        }
    }
    __syncthreads();

    // ---- head layer 2: (16,256) x (256,256), both heads -> act2 ----
    {
        f32x4 ha[2] = {z4, z4}, hv[2] = {z4, z4};
        #pragma unroll
        for (int k = 0; k < 8; ++k) {
            const int k8 = k * 4 + q;
            const bf16x8 a0 = *(const bf16x8*)(act1 + (k8 * 128 + l16) * 8);
            const bf16x8 a1 = *(const bf16x8*)(act1 + (k8 * 128 + 16 + l16) * 8);
            #pragma unroll
            for (int nt = 0; nt < 2; ++nt) {
                const int n = wave * 32 + nt * 16 + l16;
                const bf16x8 ba = *(const bf16x8*)(AW2f + ((size_t)k8 * 256 + n) * 8);
                const bf16x8 bv = *(const bf16x8*)(VW2f + ((size_t)k8 * 256 + n) * 8);
                ha[nt] = MFMA(ba, a0, ha[nt]);
                hv[nt] = MFMA(bv, a1, hv[nt]);
            }
        }
        #pragma unroll
        for (int nt = 0; nt < 2; ++nt) {
            const f32x4 ab_ = *(const f32x4*)(ab2 + wave * 32 + nt * 16 + q * 4);
            const f32x4 vb_ = *(const f32x4*)(vb2 + wave * 32 + nt * 16 + q * 4);
            float a0 = ha[nt][0] + ab_[0]; a0 = a0 > 0.f ? a0 : 0.f;
            float a1 = ha[nt][1] + ab_[1]; a1 = a1 > 0.f ? a1 : 0.f;
            float a2 = ha[nt][2] + ab_[2]; a2 = a2 > 0.f ? a2 : 0.f;
            float a3 = ha[nt][3] + ab_[3]; a3 = a3 > 0.f ? a3 : 0.f;
            float u0 = hv[nt][0] + vb_[0]; u0 = u0 > 0.f ? u0 : 0.f;
            float u1 = hv[nt][1] + vb_[1]; u1 = u1 > 0.f ? u1 : 0.f;
            float u2 = hv[nt][2] + vb_[2]; u2 = u2 > 0.f ? u2 : 0.f;
            float u3 = hv[nt][3] + vb_[3]; u3 = u3 > 0.f ? u3 : 0.f;
            const bf16x4 pa = {(__bf16)a0, (__bf16)a1, (__bf16)a2, (__bf16)a3};
            const bf16x4 pv = {(__bf16)u0, (__bf16)u1, (__bf16)u2, (__bf16)u3};
            const int c = wave * 4 + nt * 2 + qh;
            *(bf16x4*)(act2 + (c * 128 + l16) * 8 + e4)      = pa;
            *(bf16x4*)(act2 + (c * 128 + 16 + l16) * 8 + e4) = pv;
        }
    }
    __syncthreads();

    // ---- head layer 3 ----
    if (wave < 2) {       // actor logits: channel n = wave*16 + q*4 + r, batch = l16
        f32x4 acc = z4;
        #pragma unroll
        for (int k = 0; k < 8; ++k) {
            const int k8 = k * 4 + q;
            const bf16x8 a0 = *(const bf16x8*)(act2 + (k8 * 128 + l16) * 8);
            const bf16x8 bf = *(const bf16x8*)(AW3f + ((size_t)k8 * 32 + wave * 16 + l16) * 8);
            acc = MFMA(bf, a0, acc);
        }
        const int nb = wave * 16 + q * 4;
        #pragma unroll
        for (int r = 0; r < 4; ++r) {
            const int n = nb + r;
            if (n < NOUT_)
                out[(size_t)(b0 + l16) * NOUT_ + n] = acc[r] + ab3[n];
        }
    } else if (wave == 2) {  // value: channel 0 lives in q==0, reg 0
        f32x4 acc = z4;
        #pragma unroll
        for (int k = 0; k < 8; ++k) {
            const int k8 = k * 4 + q;
            const bf16x8 a1 = *(const bf16x8*)(act2 + (k8 * 128 + 16 + l16) * 8);
            const bf16x8 bf = *(const bf16x8*)(VW3f + ((size_t)k8 * 16 + l16) * 8);
            acc = MFMA(bf, a1, acc);
        }
        if (q == 0)
            out[(size_t)B_ * NOUT_ + b0 + l16] = acc[0] + vb3[0];
    }
}

extern "C" void kernel_launch(void* const* d_in, const int* in_sizes, int n_in,
                              void* d_out, int out_size, void* d_ws, size_t ws_size,
                              hipStream_t stream)
{
    const float* obs = (const float*)d_in[0];
    const float* sW1 = (const float*)d_in[1];
    const float* sb1 = (const float*)d_in[2];
    const float* sW2 = (const float*)d_in[3];
    const float* sb2 = (const float*)d_in[4];
    const float* sW3 = (const float*)d_in[5];
    const float* sb3 = (const float*)d_in[6];
    const float* aW1 = (const float*)d_in[7];
    const float* ab1 = (const float*)d_in[8];
    const float* aW2 = (const float*)d_in[9];
    const float* ab2 = (const float*)d_in[10];
    const float* aW3 = (const float*)d_in[11];
    const float* ab3 = (const float*)d_in[12];
    const float* vW1 = (const float*)d_in[13];
    const float* vb1 = (const float*)d_in[14];
    const float* vW2 = (const float*)d_in[15];
    const float* vb2 = (const float*)d_in[16];
    const float* vW3 = (const float*)d_in[17];
    const float* vb3 = (const float*)d_in[18];

    __bf16* ws = (__bf16*)d_ws;
    float* out = (float*)d_out;

    hipLaunchKernelGGL(prep_kernel, dim3(PREP_TOTAL8 / 256), dim3(256), 0, stream,
                       sW1, sW2, sW3, aW1, aW2, aW3, vW1, vW2, vW3, ws);
    hipLaunchKernelGGL(fused_kernel, dim3(B_ / 16), dim3(512), 0, stream,
                       obs, sb1, sb2, sb3, ab1, ab2, ab3, vb1, vb2, vb3,
                       (const __bf16*)ws, out);
}